// Round 1
// baseline (578.877 us; speedup 1.0000x reference)
//
#include <hip/hip_runtime.h>
#include <stdint.h>

#define M_DIM 8192
#define N_DIM 4096
#define K_DIM 4096
#define NG 32        // K_DIM / 128 groups

typedef __attribute__((ext_vector_type(4))) float  floatx4;
typedef __attribute__((ext_vector_type(8))) _Float16 halfx8;

// ---------------------------------------------------------------------------
// Conversion kernels: fp32 -> f16 (weight conversion fuses the group scales)
// ---------------------------------------------------------------------------

__global__ __launch_bounds__(256) void cvt_a_kernel(const float* __restrict__ in,
                                                    _Float16* __restrict__ out) {
    const int t = blockIdx.x * 256 + threadIdx.x;          // one 8-elem chunk per thread
    const float4* in4 = (const float4*)in;
    float4 x = in4[2 * t];
    float4 y = in4[2 * t + 1];
    union { _Float16 h[8]; uint4 u; } p;
    p.h[0] = (_Float16)x.x; p.h[1] = (_Float16)x.y;
    p.h[2] = (_Float16)x.z; p.h[3] = (_Float16)x.w;
    p.h[4] = (_Float16)y.x; p.h[5] = (_Float16)y.y;
    p.h[6] = (_Float16)y.z; p.h[7] = (_Float16)y.w;
    ((uint4*)out)[t] = p.u;
}

__global__ __launch_bounds__(256) void cvt_w_kernel(const float* __restrict__ w,
                                                    const float* __restrict__ scales,
                                                    _Float16* __restrict__ out) {
    const int t = blockIdx.x * 256 + threadIdx.x;          // 8 consecutive k of one row o
    const int o = t >> 9;                                  // (t*8) / 4096
    const int k = (t & 511) * 8;
    const float s = scales[(k >> 7) * N_DIM + o];          // scales[g, o]
    const float4* w4 = (const float4*)w;
    float4 x = w4[2 * t];
    float4 y = w4[2 * t + 1];
    union { _Float16 h[8]; uint4 u; } p;
    p.h[0] = (_Float16)(x.x * s); p.h[1] = (_Float16)(x.y * s);
    p.h[2] = (_Float16)(x.z * s); p.h[3] = (_Float16)(x.w * s);
    p.h[4] = (_Float16)(y.x * s); p.h[5] = (_Float16)(y.y * s);
    p.h[6] = (_Float16)(y.z * s); p.h[7] = (_Float16)(y.w * s);
    ((uint4*)out)[t] = p.u;
}

// ---------------------------------------------------------------------------
// f16 GEMM, m97 structure: C[m,n] = sum_k A[m,k] * B[n,k] + bias[n]
// 128x128 tile, BK=32, 256 threads (4 waves), wave = 64x64 (4x4 frags 16x16x32)
// ---------------------------------------------------------------------------

__device__ __forceinline__ void gld_lds16(const _Float16* g, _Float16* l) {
    __builtin_amdgcn_global_load_lds(
        (const __attribute__((address_space(1))) void*)g,
        (__attribute__((address_space(3))) void*)l,
        16, 0, 0);
}

__global__ __launch_bounds__(256) void gemm_f16(const _Float16* __restrict__ A,
                                                const _Float16* __restrict__ B,
                                                const float* __restrict__ bias,
                                                float* __restrict__ C) {
    __shared__ _Float16 sA[128 * 32];   // 8 KiB, row-major [row][k], NO padding
    __shared__ _Float16 sB[128 * 32];   // (global_load_lds requires contiguous layout)

    const int tid  = threadIdx.x;
    const int wave = tid >> 6;
    const int lane = tid & 63;
    const int quad = lane >> 4;
    const int l16  = lane & 15;
    const int koff = quad * 8;

    const int m0 = blockIdx.y * 128;
    const int n0 = blockIdx.x * 128;

    const int wm = (wave >> 1) * 64;    // wave's 64x64 sub-tile
    const int wn = (wave & 1) * 64;

    // staging: chunk c = issue*256 + tid covers row (c>>2), k-offset (c&3)*8
    const int c0 = tid;
    const int c1 = 256 + tid;
    const int r0 = c0 >> 2, kf0 = (c0 & 3) * 8;
    const int r1 = c1 >> 2, kf1 = (c1 & 3) * 8;

    const _Float16* Ab = A + (size_t)m0 * K_DIM;
    const _Float16* Bb = B + (size_t)n0 * K_DIM;

    // wave-uniform LDS bases (HW writes base + lane*16 bytes)
    _Float16* ldsA0 = &sA[(0 * 256 + wave * 64) * 8];
    _Float16* ldsA1 = &sA[(1 * 256 + wave * 64) * 8];
    _Float16* ldsB0 = &sB[(0 * 256 + wave * 64) * 8];
    _Float16* ldsB1 = &sB[(1 * 256 + wave * 64) * 8];

    floatx4 acc[4][4] = {};

    for (int k0 = 0; k0 < K_DIM; k0 += 32) {
        gld_lds16(Ab + (size_t)r0 * K_DIM + k0 + kf0, ldsA0);
        gld_lds16(Ab + (size_t)r1 * K_DIM + k0 + kf1, ldsA1);
        gld_lds16(Bb + (size_t)r0 * K_DIM + k0 + kf0, ldsB0);
        gld_lds16(Bb + (size_t)r1 * K_DIM + k0 + kf1, ldsB1);
        __syncthreads();   // drains vmcnt(0): global_load_lds data now visible

        halfx8 a_frag[4], b_frag[4];
#pragma unroll
        for (int i = 0; i < 4; ++i)
            a_frag[i] = *(const halfx8*)&sA[(wm + i * 16 + l16) * 32 + koff];
#pragma unroll
        for (int j = 0; j < 4; ++j)
            b_frag[j] = *(const halfx8*)&sB[(wn + j * 16 + l16) * 32 + koff];

#pragma unroll
        for (int i = 0; i < 4; ++i)
#pragma unroll
            for (int j = 0; j < 4; ++j)
                acc[i][j] = __builtin_amdgcn_mfma_f32_16x16x32_f16(
                    a_frag[i], b_frag[j], acc[i][j], 0, 0, 0);

        __syncthreads();   // protect LDS from next iteration's staging
    }

    // Epilogue: C/D layout col = lane&15, row = quad*4 + reg
#pragma unroll
    for (int i = 0; i < 4; ++i) {
        const int m = m0 + wm + i * 16 + quad * 4;
#pragma unroll
        for (int j = 0; j < 4; ++j) {
            const int n = n0 + wn + j * 16 + l16;
            const float bv = bias[n];
            float* Cp = C + (size_t)m * N_DIM + n;
#pragma unroll
            for (int r = 0; r < 4; ++r)
                Cp[(size_t)r * N_DIM] = acc[i][j][r] + bv;
        }
    }
}

// ---------------------------------------------------------------------------
// Exact fp32 fallback (only if workspace is too small) — slow but correct.
// ---------------------------------------------------------------------------

__global__ __launch_bounds__(256) void fallback_gemm(const float* __restrict__ A,
                                                     const float* __restrict__ W,
                                                     const float* __restrict__ S,
                                                     const float* __restrict__ bias,
                                                     float* __restrict__ C) {
    const long idx = (long)blockIdx.x * 256 + threadIdx.x;
    const int m = (int)(idx >> 12);
    const int n = (int)(idx & 4095);
    const float* a = A + (size_t)m * K_DIM;
    const float* w = W + (size_t)n * K_DIM;
    float acc = 0.f;
    for (int g = 0; g < NG; ++g) {
        const float s = S[g * N_DIM + n];
        float part = 0.f;
        const int kb = g * 128;
#pragma unroll 4
        for (int k = kb; k < kb + 128; ++k) part += a[k] * w[k];
        acc += part * s;
    }
    C[idx] = acc + bias[n];
}

// ---------------------------------------------------------------------------

extern "C" void kernel_launch(void* const* d_in, const int* in_sizes, int n_in,
                              void* d_out, int out_size, void* d_ws, size_t ws_size,
                              hipStream_t stream) {
    const float* input   = (const float*)d_in[0];
    const float* qweight = (const float*)d_in[1];
    const float* scales  = (const float*)d_in[2];
    const float* bias    = (const float*)d_in[3];
    float* out = (float*)d_out;

    const size_t a_bytes = (size_t)M_DIM * K_DIM * sizeof(_Float16); // 64 MiB
    const size_t w_bytes = (size_t)N_DIM * K_DIM * sizeof(_Float16); // 32 MiB

    if (ws_size >= a_bytes + w_bytes) {
        _Float16* a16 = (_Float16*)d_ws;
        _Float16* w16 = (_Float16*)((char*)d_ws + a_bytes);

        cvt_a_kernel<<<(M_DIM * (size_t)K_DIM / 8) / 256, 256, 0, stream>>>(input, a16);
        cvt_w_kernel<<<(N_DIM * (size_t)K_DIM / 8) / 256, 256, 0, stream>>>(qweight, scales, w16);

        dim3 grid(N_DIM / 128, M_DIM / 128);   // (32, 64)
        gemm_f16<<<grid, 256, 0, stream>>>(a16, w16, bias, out);
    } else {
        fallback_gemm<<<((size_t)M_DIM * N_DIM) / 256, 256, 0, stream>>>(
            input, qweight, scales, bias, out);
    }
}

// Round 3
// 571.202 us; speedup vs baseline: 1.0134x; 1.0134x over previous
//
#include <hip/hip_runtime.h>
#include <stdint.h>

#define M_DIM 8192
#define N_DIM 4096
#define K_DIM 4096

typedef __attribute__((ext_vector_type(4))) float  floatx4;
typedef __attribute__((ext_vector_type(4))) unsigned int uintx4;
typedef __attribute__((ext_vector_type(8))) _Float16 halfx8;

// ---------------------------------------------------------------------------
// Merged conversion kernel: one launch converts A (fp32->f16) and W
// (fp32 * group-scale -> f16). Nontemporal loads: the fp32 sources are dead
// after this kernel; don't let them evict the f16 outputs from L2/L3.
// ---------------------------------------------------------------------------

#define A_CHUNKS (M_DIM * K_DIM / 8)   // 4194304 chunks of 8 floats
#define W_CHUNKS (N_DIM * K_DIM / 8)   // 2097152
#define A_BLOCKS (A_CHUNKS / 256)      // 16384
#define W_BLOCKS (W_CHUNKS / 256)      // 8192

__global__ __launch_bounds__(256) void cvt_all(const float* __restrict__ a_in,
                                               const float* __restrict__ w_in,
                                               const float* __restrict__ scales,
                                               _Float16* __restrict__ a16,
                                               _Float16* __restrict__ w16) {
    const int b = blockIdx.x;
    if (b < A_BLOCKS) {
        const int t = b * 256 + threadIdx.x;
        const floatx4* in4 = (const floatx4*)a_in;
        floatx4 x = __builtin_nontemporal_load(&in4[2 * t]);
        floatx4 y = __builtin_nontemporal_load(&in4[2 * t + 1]);
        union { _Float16 h[8]; uintx4 u; } p;
        p.h[0] = (_Float16)x[0]; p.h[1] = (_Float16)x[1];
        p.h[2] = (_Float16)x[2]; p.h[3] = (_Float16)x[3];
        p.h[4] = (_Float16)y[0]; p.h[5] = (_Float16)y[1];
        p.h[6] = (_Float16)y[2]; p.h[7] = (_Float16)y[3];
        ((uintx4*)a16)[t] = p.u;                     // keep cached: gemm reads it next
    } else {
        const int t = (b - A_BLOCKS) * 256 + threadIdx.x;
        const int o = t >> 9;                        // row of W (out-feature)
        const int k = (t & 511) * 8;                 // k-offset of this chunk
        const float s = scales[(k >> 7) * N_DIM + o];
        const floatx4* w4 = (const floatx4*)w_in;
        floatx4 x = __builtin_nontemporal_load(&w4[2 * t]);
        floatx4 y = __builtin_nontemporal_load(&w4[2 * t + 1]);
        union { _Float16 h[8]; uintx4 u; } p;
        p.h[0] = (_Float16)(x[0] * s); p.h[1] = (_Float16)(x[1] * s);
        p.h[2] = (_Float16)(x[2] * s); p.h[3] = (_Float16)(x[3] * s);
        p.h[4] = (_Float16)(y[0] * s); p.h[5] = (_Float16)(y[1] * s);
        p.h[6] = (_Float16)(y[2] * s); p.h[7] = (_Float16)(y[3] * s);
        ((uintx4*)w16)[t] = p.u;
    }
}

// ---------------------------------------------------------------------------
// f16 GEMM (m97 structure) + LDS XOR-swizzle (kills 8-way bank conflicts)
// + 8x8 super-tile block swizzle (L2/L3 locality) + nontemporal C stores.
// C[m,n] = sum_k A[m,k]*B[n,k] + bias[n]
// ---------------------------------------------------------------------------

__device__ __forceinline__ void gld_lds16(const _Float16* g, _Float16* l) {
    __builtin_amdgcn_global_load_lds(
        (const __attribute__((address_space(1))) void*)g,
        (__attribute__((address_space(3))) void*)l,
        16, 0, 0);
}

__global__ __launch_bounds__(256) void gemm_f16(const _Float16* __restrict__ A,
                                                const _Float16* __restrict__ B,
                                                const float* __restrict__ bias,
                                                float* __restrict__ C) {
    __shared__ _Float16 sA[128 * 32];   // LDS slot s of row r holds global
    __shared__ _Float16 sB[128 * 32];   // k-chunk (s ^ ((r>>1)&3))  [XOR swizzle]

    const int tid  = threadIdx.x;
    const int wave = tid >> 6;
    const int lane = tid & 63;
    const int quad = lane >> 4;
    const int l16  = lane & 15;

    // Block swizzle: 64 consecutive blocks = one 8x8 (m x n) super-tile.
    const int lin = blockIdx.x;                    // 0..2047
    const int ch  = lin >> 6;                      // 0..31 super-tiles
    const int ii  = lin & 63;
    const int m0  = (((ch >> 2) << 3) + (ii >> 3)) * 128;   // 64 m-blocks
    const int n0  = (((ch & 3) << 3) + (ii & 7)) * 128;     // 32 n-blocks

    const int wm = (wave >> 1) * 64;
    const int wn = (wave & 1) * 64;

    // Staging: chunk c covers LDS (row c>>2, slot c&3); loads global k-chunk
    // ((c&3) ^ ((r>>1)&3)). The 4 lanes of a row permute within one 64B line
    // -> still fully coalesced.
    const int c0 = tid;
    const int c1 = 256 + tid;
    const int r0 = c0 >> 2, r1 = c1 >> 2;
    const int g0 = ((c0 & 3) ^ ((r0 >> 1) & 3)) * 8;
    const int g1 = ((c1 & 3) ^ ((r1 >> 1) & 3)) * 8;
    const size_t offG0 = (size_t)r0 * K_DIM + g0;
    const size_t offG1 = (size_t)r1 * K_DIM + g1;

    const _Float16* Ab = A + (size_t)m0 * K_DIM;
    const _Float16* Bb = B + (size_t)n0 * K_DIM;

    _Float16* ldsA0 = &sA[(0 * 256 + wave * 64) * 8];
    _Float16* ldsA1 = &sA[(1 * 256 + wave * 64) * 8];
    _Float16* ldsB0 = &sB[(0 * 256 + wave * 64) * 8];
    _Float16* ldsB1 = &sB[(1 * 256 + wave * 64) * 8];

    // Frag-read slot: want global k-chunk `quad` of row (wm|wn)+i*16+l16;
    // (row>>1)&3 == (l16>>1)&3 since wm, i*16 are 0 mod 8 after >>1.
    const int slot = (quad ^ ((l16 >> 1) & 3)) * 8;

    floatx4 acc[4][4] = {};

    for (int k0 = 0; k0 < K_DIM; k0 += 32) {
        gld_lds16(Ab + offG0 + k0, ldsA0);
        gld_lds16(Ab + offG1 + k0, ldsA1);
        gld_lds16(Bb + offG0 + k0, ldsB0);
        gld_lds16(Bb + offG1 + k0, ldsB1);
        __syncthreads();

        halfx8 a_frag[4], b_frag[4];
#pragma unroll
        for (int i = 0; i < 4; ++i)
            a_frag[i] = *(const halfx8*)&sA[(wm + i * 16 + l16) * 32 + slot];
#pragma unroll
        for (int j = 0; j < 4; ++j)
            b_frag[j] = *(const halfx8*)&sB[(wn + j * 16 + l16) * 32 + slot];

#pragma unroll
        for (int i = 0; i < 4; ++i)
#pragma unroll
            for (int j = 0; j < 4; ++j)
                acc[i][j] = __builtin_amdgcn_mfma_f32_16x16x32_f16(
                    a_frag[i], b_frag[j], acc[i][j], 0, 0, 0);

        __syncthreads();
    }

    // Epilogue: C/D layout col = lane&15, row = quad*4 + reg.
    // Nontemporal stores: C is write-once; keep it out of L2/L3 so A/B tiles
    // stay resident (cuts re-fetch -> shorter vmcnt drain at the barrier).
#pragma unroll
    for (int i = 0; i < 4; ++i) {
        const int m = m0 + wm + i * 16 + quad * 4;
#pragma unroll
        for (int j = 0; j < 4; ++j) {
            const int n = n0 + wn + j * 16 + l16;
            const float bv = bias[n];
            float* Cp = C + (size_t)m * N_DIM + n;
#pragma unroll
            for (int r = 0; r < 4; ++r)
                __builtin_nontemporal_store(acc[i][j][r] + bv, &Cp[(size_t)r * N_DIM]);
        }
    }
}

// ---------------------------------------------------------------------------
// Exact fp32 fallback (only if workspace is too small) — slow but correct.
// ---------------------------------------------------------------------------

__global__ __launch_bounds__(256) void fallback_gemm(const float* __restrict__ A,
                                                     const float* __restrict__ W,
                                                     const float* __restrict__ S,
                                                     const float* __restrict__ bias,
                                                     float* __restrict__ C) {
    const long idx = (long)blockIdx.x * 256 + threadIdx.x;
    const int m = (int)(idx >> 12);
    const int n = (int)(idx & 4095);
    const float* a = A + (size_t)m * K_DIM;
    const float* w = W + (size_t)n * K_DIM;
    float acc = 0.f;
    for (int g = 0; g < 32; ++g) {
        const float s = S[g * N_DIM + n];
        float part = 0.f;
        const int kb = g * 128;
#pragma unroll 4
        for (int k = kb; k < kb + 128; ++k) part += a[k] * w[k];
        acc += part * s;
    }
    C[idx] = acc + bias[n];
}

// ---------------------------------------------------------------------------

extern "C" void kernel_launch(void* const* d_in, const int* in_sizes, int n_in,
                              void* d_out, int out_size, void* d_ws, size_t ws_size,
                              hipStream_t stream) {
    const float* input   = (const float*)d_in[0];
    const float* qweight = (const float*)d_in[1];
    const float* scales  = (const float*)d_in[2];
    const float* bias    = (const float*)d_in[3];
    float* out = (float*)d_out;

    const size_t a_bytes = (size_t)M_DIM * K_DIM * sizeof(_Float16); // 64 MiB
    const size_t w_bytes = (size_t)N_DIM * K_DIM * sizeof(_Float16); // 32 MiB

    if (ws_size >= a_bytes + w_bytes) {
        _Float16* a16 = (_Float16*)d_ws;
        _Float16* w16 = (_Float16*)((char*)d_ws + a_bytes);

        cvt_all<<<A_BLOCKS + W_BLOCKS, 256, 0, stream>>>(input, qweight, scales, a16, w16);

        gemm_f16<<<2048, 256, 0, stream>>>(a16, w16, bias, out);
    } else {
        fallback_gemm<<<((size_t)M_DIM * N_DIM) / 256, 256, 0, stream>>>(
            input, qweight, scales, bias, out);
    }
}

// Round 4
// 531.688 us; speedup vs baseline: 1.0888x; 1.0743x over previous
//
#include <hip/hip_runtime.h>
#include <stdint.h>

#define M_DIM 8192
#define N_DIM 4096
#define K_DIM 4096

typedef __attribute__((ext_vector_type(4)))  float  floatx4;
typedef __attribute__((ext_vector_type(16))) float  floatx16;
typedef __attribute__((ext_vector_type(4)))  unsigned int uintx4;
typedef __attribute__((ext_vector_type(8)))  _Float16 halfx8;

// ---------------------------------------------------------------------------
// Merged conversion kernel: A (fp32->f16) and W (fp32 * group-scale -> f16).
// NT loads: fp32 sources are dead after this kernel — don't pollute L2/L3.
// ---------------------------------------------------------------------------

#define A_CHUNKS (M_DIM * K_DIM / 8)
#define W_CHUNKS (N_DIM * K_DIM / 8)
#define A_BLOCKS (A_CHUNKS / 256)      // 16384
#define W_BLOCKS (W_CHUNKS / 256)      // 8192

__global__ __launch_bounds__(256) void cvt_all(const float* __restrict__ a_in,
                                               const float* __restrict__ w_in,
                                               const float* __restrict__ scales,
                                               _Float16* __restrict__ a16,
                                               _Float16* __restrict__ w16) {
    const int b = blockIdx.x;
    if (b < A_BLOCKS) {
        const int t = b * 256 + threadIdx.x;
        const floatx4* in4 = (const floatx4*)a_in;
        floatx4 x = __builtin_nontemporal_load(&in4[2 * t]);
        floatx4 y = __builtin_nontemporal_load(&in4[2 * t + 1]);
        union { _Float16 h[8]; uintx4 u; } p;
        p.h[0] = (_Float16)x[0]; p.h[1] = (_Float16)x[1];
        p.h[2] = (_Float16)x[2]; p.h[3] = (_Float16)x[3];
        p.h[4] = (_Float16)y[0]; p.h[5] = (_Float16)y[1];
        p.h[6] = (_Float16)y[2]; p.h[7] = (_Float16)y[3];
        ((uintx4*)a16)[t] = p.u;
    } else {
        const int t = (b - A_BLOCKS) * 256 + threadIdx.x;
        const int o = t >> 9;
        const int k = (t & 511) * 8;
        const float s = scales[(k >> 7) * N_DIM + o];
        const floatx4* w4 = (const floatx4*)w_in;
        floatx4 x = __builtin_nontemporal_load(&w4[2 * t]);
        floatx4 y = __builtin_nontemporal_load(&w4[2 * t + 1]);
        union { _Float16 h[8]; uintx4 u; } p;
        p.h[0] = (_Float16)(x[0] * s); p.h[1] = (_Float16)(x[1] * s);
        p.h[2] = (_Float16)(x[2] * s); p.h[3] = (_Float16)(x[3] * s);
        p.h[4] = (_Float16)(y[0] * s); p.h[5] = (_Float16)(y[1] * s);
        p.h[6] = (_Float16)(y[2] * s); p.h[7] = (_Float16)(y[3] * s);
        ((uintx4*)w16)[t] = p.u;
    }
}

// ---------------------------------------------------------------------------
// f16 GEMM: 128x128 tile, BK=64 (half the barrier drains of BK=32),
// 32x32x16 MFMA (half the MFMA instructions, higher ceiling).
// 256 threads = 4 waves; wave covers 64x64 via 2x2 frags of 32x32.
// LDS rows are 64 halves (128 B); XOR swizzle slot^=(row&7) spreads banks.
// C[m,n] = sum_k A[m,k]*B[n,k] + bias[n]
// ---------------------------------------------------------------------------

__device__ __forceinline__ void gld_lds16(const _Float16* g, _Float16* l) {
    __builtin_amdgcn_global_load_lds(
        (const __attribute__((address_space(1))) void*)g,
        (__attribute__((address_space(3))) void*)l,
        16, 0, 0);
}

__global__ __launch_bounds__(256) void gemm_f16(const _Float16* __restrict__ A,
                                                const _Float16* __restrict__ B,
                                                const float* __restrict__ bias,
                                                float* __restrict__ C) {
    __shared__ _Float16 sA[128 * 64];   // 16 KiB each; LDS slot s of row r
    __shared__ _Float16 sB[128 * 64];   // holds global k-chunk s ^ (r&7)

    const int tid   = threadIdx.x;
    const int wave  = tid >> 6;
    const int lane  = tid & 63;
    const int l32   = lane & 31;
    const int khalf = lane >> 5;        // which 8-wide half of the 16-wide k-step

    const int m0 = blockIdx.y * 128;
    const int n0 = blockIdx.x * 128;
    const int wm = (wave >> 1) * 64;
    const int wn = (wave & 1) * 64;

    // Staging: issue q (0..3) covers chunk c = q*256 + tid.
    // row = c>>3 = q*32 + (tid>>3); LDS slot = tid&7; global chunk = slot ^ (row&7).
    // row&7 == (tid>>3)&7 for every q (q*32 ≡ 0 mod 8) -> one offset for all q.
    const int rbase = tid >> 3;                               // 0..31
    const int g8    = ((tid & 7) ^ ((tid >> 3) & 7)) * 8;     // global k-offset (halves)
    const size_t offG = (size_t)rbase * K_DIM + g8;

    const _Float16* Ab = A + (size_t)m0 * K_DIM;
    const _Float16* Bb = B + (size_t)n0 * K_DIM;

    // Wave-uniform LDS bases (HW adds lane*16 bytes): chunk (q*256 + wave*64)
    _Float16* ldsA[4];
    _Float16* ldsB[4];
#pragma unroll
    for (int q = 0; q < 4; ++q) {
        ldsA[q] = &sA[(q * 256 + wave * 64) * 8];
        ldsB[q] = &sB[(q * 256 + wave * 64) * 8];
    }

    floatx16 acc[2][2] = {};

    for (int k0 = 0; k0 < K_DIM; k0 += 64) {
#pragma unroll
        for (int q = 0; q < 4; ++q) {
            const size_t go = offG + (size_t)q * 32 * K_DIM + k0;
            gld_lds16(Ab + go, ldsA[q]);
            gld_lds16(Bb + go, ldsB[q]);
        }
        __syncthreads();

#pragma unroll
        for (int t = 0; t < 4; ++t) {            // 4 k-steps of 16
            const int slot = ((t * 2 + khalf) ^ (lane & 7)) * 8;
            halfx8 a_frag[2], b_frag[2];
#pragma unroll
            for (int i = 0; i < 2; ++i)
                a_frag[i] = *(const halfx8*)&sA[(wm + i * 32 + l32) * 64 + slot];
#pragma unroll
            for (int j = 0; j < 2; ++j)
                b_frag[j] = *(const halfx8*)&sB[(wn + j * 32 + l32) * 64 + slot];
#pragma unroll
            for (int i = 0; i < 2; ++i)
#pragma unroll
                for (int j = 0; j < 2; ++j)
                    acc[i][j] = __builtin_amdgcn_mfma_f32_32x32x16_f16(
                        a_frag[i], b_frag[j], acc[i][j], 0, 0, 0);
        }
        __syncthreads();
    }

    // Epilogue: 32x32 C/D layout col = lane&31, row = (r&3) + 8*(r>>2) + 4*(lane>>5)
#pragma unroll
    for (int i = 0; i < 2; ++i) {
#pragma unroll
        for (int j = 0; j < 2; ++j) {
            const int n = n0 + wn + j * 32 + l32;
            const float bv = bias[n];
#pragma unroll
            for (int r = 0; r < 16; ++r) {
                const int m = m0 + wm + i * 32 + (r & 3) + 8 * (r >> 2) + 4 * khalf;
                C[(size_t)m * N_DIM + n] = acc[i][j][r] + bv;
            }
        }
    }
}

// ---------------------------------------------------------------------------
// Exact fp32 fallback (only if workspace is too small) — slow but correct.
// ---------------------------------------------------------------------------

__global__ __launch_bounds__(256) void fallback_gemm(const float* __restrict__ A,
                                                     const float* __restrict__ W,
                                                     const float* __restrict__ S,
                                                     const float* __restrict__ bias,
                                                     float* __restrict__ C) {
    const long idx = (long)blockIdx.x * 256 + threadIdx.x;
    const int m = (int)(idx >> 12);
    const int n = (int)(idx & 4095);
    const float* a = A + (size_t)m * K_DIM;
    const float* w = W + (size_t)n * K_DIM;
    float acc = 0.f;
    for (int g = 0; g < 32; ++g) {
        const float s = S[g * N_DIM + n];
        float part = 0.f;
        const int kb = g * 128;
#pragma unroll 4
        for (int k = kb; k < kb + 128; ++k) part += a[k] * w[k];
        acc += part * s;
    }
    C[idx] = acc + bias[n];
}

// ---------------------------------------------------------------------------

extern "C" void kernel_launch(void* const* d_in, const int* in_sizes, int n_in,
                              void* d_out, int out_size, void* d_ws, size_t ws_size,
                              hipStream_t stream) {
    const float* input   = (const float*)d_in[0];
    const float* qweight = (const float*)d_in[1];
    const float* scales  = (const float*)d_in[2];
    const float* bias    = (const float*)d_in[3];
    float* out = (float*)d_out;

    const size_t a_bytes = (size_t)M_DIM * K_DIM * sizeof(_Float16); // 64 MiB
    const size_t w_bytes = (size_t)N_DIM * K_DIM * sizeof(_Float16); // 32 MiB

    if (ws_size >= a_bytes + w_bytes) {
        _Float16* a16 = (_Float16*)d_ws;
        _Float16* w16 = (_Float16*)((char*)d_ws + a_bytes);

        cvt_all<<<A_BLOCKS + W_BLOCKS, 256, 0, stream>>>(input, qweight, scales, a16, w16);

        dim3 grid(N_DIM / 128, M_DIM / 128);   // (32, 64)
        gemm_f16<<<grid, 256, 0, stream>>>(a16, w16, bias, out);
    } else {
        fallback_gemm<<<((size_t)M_DIM * N_DIM) / 256, 256, 0, stream>>>(
            input, qweight, scales, bias, out);
    }
}